// Round 6
// baseline (993.471 us; speedup 1.0000x reference)
//
#include <hip/hip_runtime.h>
#include <math.h>

#define HID 2048
#define NH 16
#define HD 128
#define INTER 8192
#define BB 2
#define SS 2048
#define MT (BB*SS)

typedef __bf16 bf16x8 __attribute__((ext_vector_type(8)));
typedef _Float16 f16x8 __attribute__((ext_vector_type(8)));
typedef float f32x4 __attribute__((ext_vector_type(4)));
typedef unsigned short u16x8 __attribute__((ext_vector_type(8)));

__device__ __forceinline__ float bf2f(unsigned short u) {
  unsigned v = ((unsigned)u) << 16;
  return __builtin_bit_cast(float, v);
}
__device__ __forceinline__ unsigned short f2bf(float x) {
  unsigned u = __builtin_bit_cast(unsigned, x);
  u += 0x7fffu + ((u >> 16) & 1u);
  return (unsigned short)(u >> 16);
}
__device__ __forceinline__ unsigned short f2h(float x) {
  _Float16 h = (_Float16)x;  // v_cvt_f16_f32, RTN
  return __builtin_bit_cast(unsigned short, h);
}
__device__ __forceinline__ void gll16(const void* g, const void* lds) {
  __builtin_amdgcn_global_load_lds(
      (const __attribute__((address_space(1))) void*)g,
      (__attribute__((address_space(3))) void*)lds, 16, 0, 0);
}

// ---------------- fused LayerNorm: x1 f16 (for qkv gemm), x2 bf16 ----------
__global__ __launch_bounds__(256) void ln2k(
    const float* __restrict__ X, const float* __restrict__ s1,
    const float* __restrict__ b1, const float* __restrict__ s2,
    const float* __restrict__ b2, unsigned short* __restrict__ X1f,
    unsigned short* __restrict__ X2) {
  const int row = blockIdx.x;
  const int tid = threadIdx.x;
  const float* x = X + (long)row * HID;
  float4 v0 = ((const float4*)x)[tid * 2];
  float4 v1 = ((const float4*)x)[tid * 2 + 1];
  float s = v0.x + v0.y + v0.z + v0.w + v1.x + v1.y + v1.z + v1.w;
  float q = v0.x * v0.x + v0.y * v0.y + v0.z * v0.z + v0.w * v0.w +
            v1.x * v1.x + v1.y * v1.y + v1.z * v1.z + v1.w * v1.w;
#pragma unroll
  for (int off = 1; off < 64; off <<= 1) {
    s += __shfl_xor(s, off);
    q += __shfl_xor(q, off);
  }
  __shared__ float rs[4], rq[4];
  const int wid = tid >> 6, lane = tid & 63;
  if (lane == 0) { rs[wid] = s; rq[wid] = q; }
  __syncthreads();
  s = rs[0] + rs[1] + rs[2] + rs[3];
  q = rq[0] + rq[1] + rq[2] + rq[3];
  const float mu = s * (1.f / HID);
  const float var = q * (1.f / HID) - mu * mu;
  const float rstd = rsqrtf(var + 1e-5f);
  float xv[8] = {v0.x, v0.y, v0.z, v0.w, v1.x, v1.y, v1.z, v1.w};
  u16x8 o1, o2;
#pragma unroll
  for (int e = 0; e < 8; e++) {
    const int j = tid * 8 + e;
    const float xn = (xv[e] - mu) * rstd;
    o1[e] = f2h(xn * s1[j] + b1[j]);
    o2[e] = f2bf(xn * s2[j] + b2[j]);
  }
  *(u16x8*)(X1f + (long)row * HID + tid * 8) = o1;
  *(u16x8*)(X2 + (long)row * HID + tid * 8) = o2;
}

// -- weight transpose: W[k][ldn] cols [coff,coff+N) -> WT[N][K], bf16 or f16
template <bool F16>
__global__ __launch_bounds__(256) void wtrans(const float* __restrict__ W,
                                              unsigned short* __restrict__ WT,
                                              int K, int N, int ldn, int coff) {
  (void)N;
  __shared__ float t[32][33];
  const int n0 = blockIdx.x * 32, k0 = blockIdx.y * 32;
  const int tx = threadIdx.x, ty = threadIdx.y;
#pragma unroll
  for (int r = 0; r < 4; r++)
    t[ty + r * 8][tx] = W[(long)(k0 + ty + r * 8) * ldn + coff + n0 + tx];
  __syncthreads();
#pragma unroll
  for (int r = 0; r < 4; r++) {
    const float v = t[tx][ty + r * 8];
    WT[(long)(n0 + ty + r * 8) * K + k0 + tx] = F16 ? f2h(v) : f2bf(v);
  }
}

// ---------------- rope cos/sin table (f64 angle for accuracy) --------------
__global__ void rope_tab(float2* __restrict__ rope) {
  const int s = blockIdx.x, i = threadIdx.x;  // 2048 x 64
  const double ang = (double)s * pow(10000.0, -(double)i / 64.0);
  rope[s * 64 + i] = make_float2((float)cos(ang), (float)sin(ang));
}

// ---- f16 GEMM for all of qkv + fused RoPE epilogue ------------------------
// C[4096][6144] = A[M][K](f16) @ Bt[N][K](f16)^T + bias.
// cols 0..4095: rope pair-rotation, write f16 Q/K in [bh][s][128];
// cols 4096..6143: write bf16 V [m][2048].
__global__ __launch_bounds__(256) void gemmqkv(
    const unsigned short* __restrict__ A, const unsigned short* __restrict__ Bt,
    const float* __restrict__ bias, const float2* __restrict__ rope,
    unsigned short* __restrict__ QF, unsigned short* __restrict__ KF,
    unsigned short* __restrict__ Vb) {
  __shared__ unsigned short As[128 * 64];
  __shared__ unsigned short Bs[128 * 64];
  const int K = HID;
  const int tid = threadIdx.x;
  const int wid = tid >> 6, lane = tid & 63;
  const int l16 = lane & 15, lhi = lane >> 4;
  const int bn = blockIdx.x, bm = blockIdx.y;
  const int wr = wid >> 1, wc = wid & 1;
  const long rA0 = (long)bm * 128;
  const long rB0 = (long)bn * 128;

  f32x4 acc[4][4] = {};

  for (int kt = 0; kt < K; kt += 64) {
#pragma unroll
    for (int i = 0; i < 4; i++) {
      const int lin = i * 4096 + wid * 1024 + (lane << 4);
      const int row = lin >> 7;
      const int cs = ((lin >> 4) & 7) ^ (row & 7);
      gll16(A + (rA0 + row) * (long)K + kt + cs * 8,
            (const char*)As + (i * 4096 + wid * 1024));
      gll16(Bt + (rB0 + row) * (long)K + kt + cs * 8,
            (const char*)Bs + (i * 4096 + wid * 1024));
    }
    __syncthreads();
#pragma unroll
    for (int ks = 0; ks < 2; ks++) {
      f16x8 av[4], bv[4];
#pragma unroll
      for (int m = 0; m < 4; m++) {
        const int row = wr * 64 + m * 16 + l16;
        const int ch = (ks * 4 + lhi) ^ (row & 7);
        av[m] = *(const f16x8*)((const char*)As + row * 128 + ch * 16);
      }
#pragma unroll
      for (int n = 0; n < 4; n++) {
        const int row = wc * 64 + n * 16 + l16;
        const int ch = (ks * 4 + lhi) ^ (row & 7);
        bv[n] = *(const f16x8*)((const char*)Bs + row * 128 + ch * 16);
      }
#pragma unroll
      for (int m = 0; m < 4; m++)
#pragma unroll
        for (int n = 0; n < 4; n++)
          acc[m][n] = __builtin_amdgcn_mfma_f32_16x16x32_f16(av[m], bv[n],
                                                             acc[m][n], 0, 0, 0);
    }
    __syncthreads();
  }

  // epilogue (block-uniform segment: q, k, or v)
  const int b_ = (int)(rA0 >> 11);
#pragma unroll
  for (int m = 0; m < 4; m++) {
#pragma unroll
    for (int n = 0; n < 4; n++) {
      const int col = (int)rB0 + wc * 64 + n * 16 + l16;
      const float bsv = bias[col];
      const int cq = col & 2047;
      const int i = (cq & 127) >> 1;
      const int hh = (cq >> 7) & 15;
      const int d = cq & 127;
#pragma unroll
      for (int r = 0; r < 4; r++) {
        const int row = (int)rA0 + wr * 64 + m * 16 + lhi * 4 + r;
        const int srow = row & 2047;
        const float v = acc[m][n][r] + bsv;
        if (col < 4096) {
          const float p = __shfl_xor(v, 1);
          const float2 cs = rope[srow * 64 + i];
          const float o = ((lane & 1) == 0) ? (v * cs.x - p * cs.y)
                                            : (p * cs.y + v * cs.x);
          unsigned short* dst = (col < 2048) ? QF : KF;
          dst[((long)(b_ * NH + hh) * SS + srow) * HD + d] = f2h(o);
        } else {
          Vb[(long)row * HID + (col - 4096)] = f2bf(v);
        }
      }
    }
  }
}

// ---------------- V transpose: Vbf [m][2048] -> VT [bh][128][s] ------------
__global__ __launch_bounds__(256) void vtrans(
    const unsigned short* __restrict__ Vb, unsigned short* __restrict__ VTb) {
  __shared__ unsigned short t[32][33];
  const int bh = blockIdx.z, b = bh >> 4, h = bh & 15;
  const int d0 = blockIdx.x * 32, s0 = blockIdx.y * 32;
  const int tx = threadIdx.x, ty = threadIdx.y;
#pragma unroll
  for (int r = 0; r < 4; r++) {
    const int s = s0 + ty + r * 8;
    t[ty + r * 8][tx] = Vb[((long)(b * SS + s)) * HID + h * HD + d0 + tx];
  }
  __syncthreads();
#pragma unroll
  for (int r = 0; r < 4; r++) {
    const int d = d0 + ty + r * 8;
    VTb[((long)bh * HD + d) * SS + s0 + tx] = t[tx][ty + r * 8];
  }
}

// ---------------- 128x128-tile plain bf16 GEMM ----------------
// MODE 0: bf16 out; 1: gelu+bf16; 2: +residF(f32)+residB(bf16), f32 out.
template <int MODE>
__global__ __launch_bounds__(256) void gemm128(
    const unsigned short* __restrict__ A, const unsigned short* __restrict__ Bt,
    const float* __restrict__ bias, void* __restrict__ Cout, int M, int N,
    int K, const float* __restrict__ residF,
    const unsigned short* __restrict__ residB) {
  (void)M;
  __shared__ unsigned short As[128 * 64];
  __shared__ unsigned short Bs[128 * 64];
  const int tid = threadIdx.x;
  const int wid = tid >> 6, lane = tid & 63;
  const int l16 = lane & 15, lhi = lane >> 4;
  const int bn = blockIdx.x, bm = blockIdx.y;
  const int wr = wid >> 1, wc = wid & 1;
  const long rA0 = (long)bm * 128;
  const long rB0 = (long)bn * 128;

  f32x4 acc[4][4] = {};

  for (int kt = 0; kt < K; kt += 64) {
#pragma unroll
    for (int i = 0; i < 4; i++) {
      const int lin = i * 4096 + wid * 1024 + (lane << 4);
      const int row = lin >> 7;
      const int cs = ((lin >> 4) & 7) ^ (row & 7);
      gll16(A + (rA0 + row) * (long)K + kt + cs * 8,
            (const char*)As + (i * 4096 + wid * 1024));
      gll16(Bt + (rB0 + row) * (long)K + kt + cs * 8,
            (const char*)Bs + (i * 4096 + wid * 1024));
    }
    __syncthreads();
#pragma unroll
    for (int ks = 0; ks < 2; ks++) {
      bf16x8 av[4], bv[4];
#pragma unroll
      for (int m = 0; m < 4; m++) {
        const int row = wr * 64 + m * 16 + l16;
        const int ch = (ks * 4 + lhi) ^ (row & 7);
        av[m] = *(const bf16x8*)((const char*)As + row * 128 + ch * 16);
      }
#pragma unroll
      for (int n = 0; n < 4; n++) {
        const int row = wc * 64 + n * 16 + l16;
        const int ch = (ks * 4 + lhi) ^ (row & 7);
        bv[n] = *(const bf16x8*)((const char*)Bs + row * 128 + ch * 16);
      }
#pragma unroll
      for (int m = 0; m < 4; m++)
#pragma unroll
        for (int n = 0; n < 4; n++)
          acc[m][n] = __builtin_amdgcn_mfma_f32_16x16x32_bf16(av[m], bv[n],
                                                              acc[m][n], 0, 0, 0);
    }
    __syncthreads();
  }

#pragma unroll
  for (int m = 0; m < 4; m++) {
#pragma unroll
    for (int n = 0; n < 4; n++) {
      const long col = rB0 + wc * 64 + n * 16 + l16;
      const float bsv = bias[col];
#pragma unroll
      for (int r = 0; r < 4; r++) {
        const long row = rA0 + wr * 64 + m * 16 + lhi * 4 + r;
        float v = acc[m][n][r] + bsv;
        if (MODE == 1) v = 0.5f * v * (1.f + erff(v * 0.7071067811865475f));
        if (MODE == 2) {
          v += residF[row * N + col] + bf2f(residB[row * N + col]);
          ((float*)Cout)[row * N + col] = v;
        } else {
          ((unsigned short*)Cout)[row * N + col] = f2bf(v);
        }
      }
    }
  }
}

// -- flash v4: f16 QK^T single-term, KVBLK=32, 3 blocks/CU, counted vmcnt ---
// QF/KF: [bh][s][128] f16; VT: [bh][128][s] bf16; AO: [b][s][h*128+d] bf16
__global__ __launch_bounds__(256, 3) void flash(
    const unsigned short* __restrict__ QF, const unsigned short* __restrict__ KF,
    const unsigned short* __restrict__ VT, const float* __restrict__ amask,
    unsigned short* __restrict__ AO) {
  __shared__ unsigned short Kt[2][32 * 128];  // 16KB [key][d] f16, dbuf
  __shared__ unsigned short Vt[2][128 * 32];  // 16KB [d][key] bf16, dbuf
  __shared__ unsigned short Pl[4 * 1024];     //  8KB per-wave 32x32 P bf16
  __shared__ float maskL[SS];                 //  8KB amask*log2e => 48KB total
  const int bh = blockIdx.y;
  // big+small qt pairing: co-resident blocks get complementary work
  const int qt = (bh >= 16) ? blockIdx.x : (15 - blockIdx.x);
  const int b = bh >> 4, h = bh & 15;
  const int tid = threadIdx.x, wid = tid >> 6, lane = tid & 63;
  const int l16 = lane & 15, lhi = lane >> 4;
  const unsigned short* Qfb = QF + (long)bh * SS * HD;
  const unsigned short* Kfb = KF + (long)bh * SS * HD;
  const unsigned short* Vb = VT + (long)bh * HD * SS;
  const int q0 = qt * 128 + wid * 32;
  const float LOG2E = 1.4426950408889634f;
  const float SCL2 = 16.322232154552f;  // sqrt(128)*log2e

  {  // amask row -> LDS (prescaled); K-loop stays free of global loads
    const float4* mg = (const float4*)(amask + (long)b * SS);
    float4 m0 = mg[tid * 2], m1 = mg[tid * 2 + 1];
    m0.x *= LOG2E; m0.y *= LOG2E; m0.z *= LOG2E; m0.w *= LOG2E;
    m1.x *= LOG2E; m1.y *= LOG2E; m1.z *= LOG2E; m1.w *= LOG2E;
    ((float4*)maskL)[tid * 2] = m0;
    ((float4*)maskL)[tid * 2 + 1] = m1;
  }

  f16x8 qf[2][4];
#pragma unroll
  for (int mf = 0; mf < 2; mf++)
#pragma unroll
    for (int ks = 0; ks < 4; ks++)
      qf[mf][ks] = *(const f16x8*)(Qfb + (long)(q0 + mf * 16 + l16) * HD +
                                   ks * 32 + lhi * 8);

  // stage tile kt2 (32 keys): 4 loads/thread = 16KB/block
  auto stage = [&](int kt2, int bu) {
#pragma unroll
    for (int i = 0; i < 2; i++) {
      const int lin = i * 4096 + wid * 1024 + (lane << 4);
      const int dst = i * 4096 + wid * 1024;
      {
        const int row = lin >> 8;  // K rows are 256B (128 f16)
        const int cs = ((lin >> 4) & 15) ^ (row & 7);
        gll16(Kfb + (long)(kt2 * 32 + row) * HD + cs * 8,
              (const char*)Kt[bu] + dst);
      }
      {
        const int row = lin >> 6;  // V rows are 64B (32 bf16 keys)
        const int cs = ((lin >> 4) & 3) ^ ((row >> 1) & 3);
        gll16(Vb + (long)row * SS + kt2 * 32 + cs * 8, (const char*)Vt[bu] + dst);
      }
    }
  };

  f32x4 accO[2][8] = {};
  float mrow[2][4], lrow[2][4];
#pragma unroll
  for (int mf = 0; mf < 2; mf++)
#pragma unroll
    for (int r = 0; r < 4; r++) { mrow[mf][r] = -3e38f; lrow[mf][r] = 0.f; }

  const int nkt = 4 * qt + 4;
  stage(0, 0);
  asm volatile("s_waitcnt lgkmcnt(0)" ::: "memory");  // maskL writes done
  int buf = 0;
  for (int kt = 0; kt < nkt; kt++) {
    if (kt + 1 < nkt) {
      stage(kt + 1, buf ^ 1);  // 4 loads stay in flight across the barrier
      asm volatile("s_waitcnt vmcnt(4)" ::: "memory");  // tile kt landed
    } else {
      asm volatile("s_waitcnt vmcnt(0)" ::: "memory");
    }
    __builtin_amdgcn_s_barrier();  // raw barrier: no vmcnt(0) drain

    // wave-uniform skip of fully-masked tiles (keys all > wave's last row)
    const bool active = (kt * 32 <= q0 + 31);
    if (active) {
      // S = Q K^T (f16, single term, 16 MFMAs)
      f32x4 accS[2][2] = {};
      __builtin_amdgcn_s_setprio(1);
#pragma unroll
      for (int ks = 0; ks < 4; ks++) {
        f16x8 bk[2];
#pragma unroll
        for (int nf = 0; nf < 2; nf++) {
          const int row = nf * 16 + l16;
          const int ch = (ks * 4 + lhi) ^ (row & 7);
          bk[nf] = *(const f16x8*)((const char*)Kt[buf] + row * 256 + ch * 16);
        }
#pragma unroll
        for (int mf = 0; mf < 2; mf++)
#pragma unroll
          for (int nf = 0; nf < 2; nf++)
            accS[mf][nf] = __builtin_amdgcn_mfma_f32_16x16x32_f16(
                qf[mf][ks], bk[nf], accS[mf][nf], 0, 0, 0);
      }
      __builtin_amdgcn_s_setprio(0);

      // scale to log2 domain + mask + causal
      float mk[2];
      mk[0] = maskL[kt * 32 + l16];
      mk[1] = maskL[kt * 32 + 16 + l16];
#pragma unroll
      for (int mf = 0; mf < 2; mf++)
#pragma unroll
        for (int nf = 0; nf < 2; nf++)
#pragma unroll
          for (int r = 0; r < 4; r++) {
            const int key = kt * 32 + nf * 16 + l16;
            const int qg = q0 + mf * 16 + lhi * 4 + r;
            const float sv = accS[mf][nf][r] * SCL2 + mk[nf];
            accS[mf][nf][r] = (key > qg) ? -1e30f : sv;
          }

      // row maxes over the 16-lane group
      float mx[2][4];
#pragma unroll
      for (int mf = 0; mf < 2; mf++)
#pragma unroll
        for (int r = 0; r < 4; r++) {
          float m0 = fmaxf(accS[mf][0][r], accS[mf][1][r]);
          m0 = fmaxf(m0, __shfl_xor(m0, 1));
          m0 = fmaxf(m0, __shfl_xor(m0, 2));
          m0 = fmaxf(m0, __shfl_xor(m0, 4));
          m0 = fmaxf(m0, __shfl_xor(m0, 8));
          mx[mf][r] = m0;
        }
      // defer-rescale (THR=8 in log2 domain)
      bool defer = true;
#pragma unroll
      for (int mf = 0; mf < 2; mf++)
#pragma unroll
        for (int r = 0; r < 4; r++)
          defer = defer && (mx[mf][r] <= mrow[mf][r] + 8.f);
      if (!__all(defer)) {
#pragma unroll
        for (int mf = 0; mf < 2; mf++)
#pragma unroll
          for (int r = 0; r < 4; r++) {
            const float mnew = fmaxf(mrow[mf][r], mx[mf][r]);
            const float alpha = exp2f(mrow[mf][r] - mnew);
            mrow[mf][r] = mnew;
            lrow[mf][r] *= alpha;
#pragma unroll
            for (int nf2 = 0; nf2 < 8; nf2++) accO[mf][nf2][r] *= alpha;
          }
      }
      // P = exp2(S - m) -> per-wave LDS (32x32 bf16, swizzled)
#pragma unroll
      for (int mf = 0; mf < 2; mf++)
#pragma unroll
        for (int r = 0; r < 4; r++) {
          const int rowl = mf * 16 + lhi * 4 + r;
          const int qg = q0 + rowl;
          float rsum = 0.f;
#pragma unroll
          for (int nf = 0; nf < 2; nf++) {
            const int key = kt * 32 + nf * 16 + l16;
            const float p =
                (key > qg) ? 0.f : exp2f(accS[mf][nf][r] - mrow[mf][r]);
            rsum += p;
            const int colv = nf * 16 + l16;
            const int slot = (colv >> 3) ^ ((rowl >> 1) & 3);
            *(unsigned short*)((char*)Pl + wid * 2048 + rowl * 64 + slot * 16 +
                               (colv & 7) * 2) = f2bf(p);
          }
          rsum += __shfl_xor(rsum, 1);
          rsum += __shfl_xor(rsum, 2);
          rsum += __shfl_xor(rsum, 4);
          rsum += __shfl_xor(rsum, 8);
          lrow[mf][r] += rsum;
        }

      // O += P V  (16 MFMAs, bf16)
      __builtin_amdgcn_s_setprio(1);
      {
        bf16x8 pa[2];
#pragma unroll
        for (int mf = 0; mf < 2; mf++) {
          const int rowp = mf * 16 + l16;
          const int ch = lhi ^ ((rowp >> 1) & 3);
          pa[mf] = *(const bf16x8*)((const char*)Pl + wid * 2048 + rowp * 64 +
                                    ch * 16);
        }
#pragma unroll
        for (int nf2 = 0; nf2 < 8; nf2++) {
          const int rowv = nf2 * 16 + l16;
          const int ch = lhi ^ ((rowv >> 1) & 3);
          bf16x8 vv =
              *(const bf16x8*)((const char*)Vt[buf] + rowv * 64 + ch * 16);
#pragma unroll
          for (int mf = 0; mf < 2; mf++)
            accO[mf][nf2] = __builtin_amdgcn_mfma_f32_16x16x32_bf16(
                pa[mf], vv, accO[mf][nf2], 0, 0, 0);
        }
      }
      __builtin_amdgcn_s_setprio(0);
    }  // active
    __builtin_amdgcn_s_barrier();  // all waves done with buf before restage
    buf ^= 1;
  }

#pragma unroll
  for (int mf = 0; mf < 2; mf++)
#pragma unroll
    for (int nf2 = 0; nf2 < 8; nf2++)
#pragma unroll
      for (int r = 0; r < 4; r++) {
        const int qg = q0 + mf * 16 + lhi * 4 + r;
        const int d = nf2 * 16 + l16;
        const float v = accO[mf][nf2][r] / lrow[mf][r];
        AO[((long)(b * SS + qg)) * HID + h * HD + d] = f2bf(v);
      }
}

extern "C" void kernel_launch(void* const* d_in, const int* in_sizes, int n_in,
                              void* d_out, int out_size, void* d_ws,
                              size_t ws_size, hipStream_t stream) {
  (void)in_sizes; (void)n_in; (void)out_size;
  const float* hidden = (const float*)d_in[0];
  const float* amask = (const float*)d_in[1];
  const float* w_qkv = (const float*)d_in[2];
  const float* b_qkv = (const float*)d_in[3];
  const float* w_o = (const float*)d_in[4];
  const float* b_o = (const float*)d_in[5];
  const float* ln1s = (const float*)d_in[6];
  const float* ln1b = (const float*)d_in[7];
  const float* ln2s = (const float*)d_in[8];
  const float* ln2b = (const float*)d_in[9];
  const float* w_in = (const float*)d_in[10];
  const float* b_in = (const float*)d_in[11];
  const float* w_out = (const float*)d_in[12];
  const float* b_out = (const float*)d_in[13];

  char* ws = (char*)d_ws;
  // liveness-aliased workspace (<=170MB; >=209MB verified available)
  unsigned short* X1f = (unsigned short*)(ws + 0);           // 16MB f16, later AO
  unsigned short* X2  = (unsigned short*)(ws + 16777216);    // 16MB bf16
  unsigned short* Vbf = (unsigned short*)(ws + 33554432);    // 16MB bf16
  unsigned short* WQ  = (unsigned short*)(ws + 50331648);    // 24MB f16 [6144][2048]
  unsigned short* QFb = (unsigned short*)(ws + 75497472);    // 16MB f16
  unsigned short* KFb = (unsigned short*)(ws + 92274688);    // 16MB f16
  unsigned short* VTb = (unsigned short*)(ws + 109051904);   // 16MB bf16
  unsigned short* ATT = (unsigned short*)(ws + 125829120);   // 16MB bf16
  unsigned short* WD  = (unsigned short*)(ws + 142606336);   // 32MB bf16 (Wo/Win/Wout)
  float2* ROPE = (float2*)(ws + 176160768);                  // 1MB
  if (ws_size < 177209344) return;

  unsigned short* AO = X1f;  // x1 dead after gemmqkv
  unsigned short* H1 = WQ;   // WQ+QF+KF(+VTb head) dead after flash: 64MB

  ln2k<<<MT, 256, 0, stream>>>(hidden, ln1s, ln1b, ln2s, ln2b, X1f, X2);
  rope_tab<<<SS, 64, 0, stream>>>(ROPE);
  // qkv: one f16 GEMM, rope fused for q,k
  wtrans<true><<<dim3(192, 64), dim3(32, 8), 0, stream>>>(w_qkv, WQ, HID,
                                                          3 * HID, 3 * HID, 0);
  gemmqkv<<<dim3(48, 32), 256, 0, stream>>>(X1f, WQ, b_qkv, ROPE, QFb, KFb,
                                            Vbf);
  vtrans<<<dim3(4, 64, 32), dim3(32, 8), 0, stream>>>(Vbf, VTb);
  flash<<<dim3(16, 32), 256, 0, stream>>>(QFb, KFb, VTb, amask, AO);
  // attention projection
  wtrans<false><<<dim3(64, 64), dim3(32, 8), 0, stream>>>(w_o, WD, HID, HID,
                                                          HID, 0);
  gemm128<0><<<dim3(16, 32), 256, 0, stream>>>(AO, WD, b_o, ATT, MT, HID, HID,
                                               nullptr, nullptr);
  // mlp
  wtrans<false><<<dim3(256, 64), dim3(32, 8), 0, stream>>>(w_in, WD, HID,
                                                           INTER, INTER, 0);
  gemm128<1><<<dim3(64, 32), 256, 0, stream>>>(X2, WD, b_in, H1, MT, INTER,
                                               HID, nullptr, nullptr);
  wtrans<false><<<dim3(64, 256), dim3(32, 8), 0, stream>>>(w_out, WD, INTER,
                                                           HID, HID, 0);
  gemm128<2><<<dim3(16, 32), 256, 0, stream>>>(H1, WD, b_out, d_out, MT, HID,
                                               INTER, hidden, ATT);
}

// Round 7
// 756.197 us; speedup vs baseline: 1.3138x; 1.3138x over previous
//
#include <hip/hip_runtime.h>
#include <math.h>

#define HID 2048
#define NH 16
#define HD 128
#define INTER 8192
#define BB 2
#define SS 2048
#define MT (BB*SS)

typedef __bf16 bf16x8 __attribute__((ext_vector_type(8)));
typedef _Float16 f16x8 __attribute__((ext_vector_type(8)));
typedef float f32x4 __attribute__((ext_vector_type(4)));
typedef unsigned short u16x8 __attribute__((ext_vector_type(8)));

__device__ __forceinline__ float bf2f(unsigned short u) {
  unsigned v = ((unsigned)u) << 16;
  return __builtin_bit_cast(float, v);
}
__device__ __forceinline__ unsigned short f2bf(float x) {
  unsigned u = __builtin_bit_cast(unsigned, x);
  u += 0x7fffu + ((u >> 16) & 1u);
  return (unsigned short)(u >> 16);
}
__device__ __forceinline__ unsigned short f2h(float x) {
  _Float16 h = (_Float16)x;  // v_cvt_f16_f32, RTN
  return __builtin_bit_cast(unsigned short, h);
}
__device__ __forceinline__ void gll16(const void* g, const void* lds) {
  __builtin_amdgcn_global_load_lds(
      (const __attribute__((address_space(1))) void*)g,
      (__attribute__((address_space(3))) void*)lds, 16, 0, 0);
}

// ---------------- fused LayerNorm: x1 f16 (for qkv gemm), x2 bf16 ----------
__global__ __launch_bounds__(256) void ln2k(
    const float* __restrict__ X, const float* __restrict__ s1,
    const float* __restrict__ b1, const float* __restrict__ s2,
    const float* __restrict__ b2, unsigned short* __restrict__ X1f,
    unsigned short* __restrict__ X2) {
  const int row = blockIdx.x;
  const int tid = threadIdx.x;
  const float* x = X + (long)row * HID;
  float4 v0 = ((const float4*)x)[tid * 2];
  float4 v1 = ((const float4*)x)[tid * 2 + 1];
  float s = v0.x + v0.y + v0.z + v0.w + v1.x + v1.y + v1.z + v1.w;
  float q = v0.x * v0.x + v0.y * v0.y + v0.z * v0.z + v0.w * v0.w +
            v1.x * v1.x + v1.y * v1.y + v1.z * v1.z + v1.w * v1.w;
#pragma unroll
  for (int off = 1; off < 64; off <<= 1) {
    s += __shfl_xor(s, off);
    q += __shfl_xor(q, off);
  }
  __shared__ float rs[4], rq[4];
  const int wid = tid >> 6, lane = tid & 63;
  if (lane == 0) { rs[wid] = s; rq[wid] = q; }
  __syncthreads();
  s = rs[0] + rs[1] + rs[2] + rs[3];
  q = rq[0] + rq[1] + rq[2] + rq[3];
  const float mu = s * (1.f / HID);
  const float var = q * (1.f / HID) - mu * mu;
  const float rstd = rsqrtf(var + 1e-5f);
  float xv[8] = {v0.x, v0.y, v0.z, v0.w, v1.x, v1.y, v1.z, v1.w};
  u16x8 o1, o2;
#pragma unroll
  for (int e = 0; e < 8; e++) {
    const int j = tid * 8 + e;
    const float xn = (xv[e] - mu) * rstd;
    o1[e] = f2h(xn * s1[j] + b1[j]);
    o2[e] = f2bf(xn * s2[j] + b2[j]);
  }
  *(u16x8*)(X1f + (long)row * HID + tid * 8) = o1;
  *(u16x8*)(X2 + (long)row * HID + tid * 8) = o2;
}

// -- weight transpose: W[k][ldn] cols [coff,coff+N) -> WT[N][K], bf16 or f16
template <bool F16>
__global__ __launch_bounds__(256) void wtrans(const float* __restrict__ W,
                                              unsigned short* __restrict__ WT,
                                              int K, int N, int ldn, int coff) {
  (void)N;
  __shared__ float t[32][33];
  const int n0 = blockIdx.x * 32, k0 = blockIdx.y * 32;
  const int tx = threadIdx.x, ty = threadIdx.y;
#pragma unroll
  for (int r = 0; r < 4; r++)
    t[ty + r * 8][tx] = W[(long)(k0 + ty + r * 8) * ldn + coff + n0 + tx];
  __syncthreads();
#pragma unroll
  for (int r = 0; r < 4; r++) {
    const float v = t[tx][ty + r * 8];
    WT[(long)(n0 + ty + r * 8) * K + k0 + tx] = F16 ? f2h(v) : f2bf(v);
  }
}

// ---------------- rope cos/sin table (f64 angle for accuracy) --------------
__global__ void rope_tab(float2* __restrict__ rope) {
  const int s = blockIdx.x, i = threadIdx.x;  // 2048 x 64
  const double ang = (double)s * pow(10000.0, -(double)i / 64.0);
  rope[s * 64 + i] = make_float2((float)cos(ang), (float)sin(ang));
}

// ---- f16 GEMM for all of qkv + fused RoPE epilogue ------------------------
__global__ __launch_bounds__(256) void gemmqkv(
    const unsigned short* __restrict__ A, const unsigned short* __restrict__ Bt,
    const float* __restrict__ bias, const float2* __restrict__ rope,
    unsigned short* __restrict__ QF, unsigned short* __restrict__ KF,
    unsigned short* __restrict__ Vb) {
  __shared__ unsigned short As[128 * 64];
  __shared__ unsigned short Bs[128 * 64];
  const int K = HID;
  const int tid = threadIdx.x;
  const int wid = tid >> 6, lane = tid & 63;
  const int l16 = lane & 15, lhi = lane >> 4;
  const int bn = blockIdx.x, bm = blockIdx.y;
  const int wr = wid >> 1, wc = wid & 1;
  const long rA0 = (long)bm * 128;
  const long rB0 = (long)bn * 128;

  f32x4 acc[4][4] = {};

  for (int kt = 0; kt < K; kt += 64) {
#pragma unroll
    for (int i = 0; i < 4; i++) {
      const int lin = i * 4096 + wid * 1024 + (lane << 4);
      const int row = lin >> 7;
      const int cs = ((lin >> 4) & 7) ^ (row & 7);
      gll16(A + (rA0 + row) * (long)K + kt + cs * 8,
            (const char*)As + (i * 4096 + wid * 1024));
      gll16(Bt + (rB0 + row) * (long)K + kt + cs * 8,
            (const char*)Bs + (i * 4096 + wid * 1024));
    }
    __syncthreads();
#pragma unroll
    for (int ks = 0; ks < 2; ks++) {
      f16x8 av[4], bv[4];
#pragma unroll
      for (int m = 0; m < 4; m++) {
        const int row = wr * 64 + m * 16 + l16;
        const int ch = (ks * 4 + lhi) ^ (row & 7);
        av[m] = *(const f16x8*)((const char*)As + row * 128 + ch * 16);
      }
#pragma unroll
      for (int n = 0; n < 4; n++) {
        const int row = wc * 64 + n * 16 + l16;
        const int ch = (ks * 4 + lhi) ^ (row & 7);
        bv[n] = *(const f16x8*)((const char*)Bs + row * 128 + ch * 16);
      }
#pragma unroll
      for (int m = 0; m < 4; m++)
#pragma unroll
        for (int n = 0; n < 4; n++)
          acc[m][n] = __builtin_amdgcn_mfma_f32_16x16x32_f16(av[m], bv[n],
                                                             acc[m][n], 0, 0, 0);
    }
    __syncthreads();
  }

  const int b_ = (int)(rA0 >> 11);
#pragma unroll
  for (int m = 0; m < 4; m++) {
#pragma unroll
    for (int n = 0; n < 4; n++) {
      const int col = (int)rB0 + wc * 64 + n * 16 + l16;
      const float bsv = bias[col];
      const int cq = col & 2047;
      const int i = (cq & 127) >> 1;
      const int hh = (cq >> 7) & 15;
      const int d = cq & 127;
#pragma unroll
      for (int r = 0; r < 4; r++) {
        const int row = (int)rA0 + wr * 64 + m * 16 + lhi * 4 + r;
        const int srow = row & 2047;
        const float v = acc[m][n][r] + bsv;
        if (col < 4096) {
          const float p = __shfl_xor(v, 1);
          const float2 cs = rope[srow * 64 + i];
          const float o = ((lane & 1) == 0) ? (v * cs.x - p * cs.y)
                                            : (p * cs.y + v * cs.x);
          unsigned short* dst = (col < 2048) ? QF : KF;
          dst[((long)(b_ * NH + hh) * SS + srow) * HD + d] = f2h(o);
        } else {
          Vb[(long)row * HID + (col - 4096)] = f2bf(v);
        }
      }
    }
  }
}

// ---------------- V transpose: Vbf [m][2048] -> VT [bh][128][s] ------------
__global__ __launch_bounds__(256) void vtrans(
    const unsigned short* __restrict__ Vb, unsigned short* __restrict__ VTb) {
  __shared__ unsigned short t[32][33];
  const int bh = blockIdx.z, b = bh >> 4, h = bh & 15;
  const int d0 = blockIdx.x * 32, s0 = blockIdx.y * 32;
  const int tx = threadIdx.x, ty = threadIdx.y;
#pragma unroll
  for (int r = 0; r < 4; r++) {
    const int s = s0 + ty + r * 8;
    t[ty + r * 8][tx] = Vb[((long)(b * SS + s)) * HID + h * HD + d0 + tx];
  }
  __syncthreads();
#pragma unroll
  for (int r = 0; r < 4; r++) {
    const int d = d0 + ty + r * 8;
    VTb[((long)bh * HD + d) * SS + s0 + tx] = t[tx][ty + r * 8];
  }
}

// ---------------- 128x128-tile plain bf16 GEMM ----------------
template <int MODE>
__global__ __launch_bounds__(256) void gemm128(
    const unsigned short* __restrict__ A, const unsigned short* __restrict__ Bt,
    const float* __restrict__ bias, void* __restrict__ Cout, int M, int N,
    int K, const float* __restrict__ residF,
    const unsigned short* __restrict__ residB) {
  (void)M;
  __shared__ unsigned short As[128 * 64];
  __shared__ unsigned short Bs[128 * 64];
  const int tid = threadIdx.x;
  const int wid = tid >> 6, lane = tid & 63;
  const int l16 = lane & 15, lhi = lane >> 4;
  const int bn = blockIdx.x, bm = blockIdx.y;
  const int wr = wid >> 1, wc = wid & 1;
  const long rA0 = (long)bm * 128;
  const long rB0 = (long)bn * 128;

  f32x4 acc[4][4] = {};

  for (int kt = 0; kt < K; kt += 64) {
#pragma unroll
    for (int i = 0; i < 4; i++) {
      const int lin = i * 4096 + wid * 1024 + (lane << 4);
      const int row = lin >> 7;
      const int cs = ((lin >> 4) & 7) ^ (row & 7);
      gll16(A + (rA0 + row) * (long)K + kt + cs * 8,
            (const char*)As + (i * 4096 + wid * 1024));
      gll16(Bt + (rB0 + row) * (long)K + kt + cs * 8,
            (const char*)Bs + (i * 4096 + wid * 1024));
    }
    __syncthreads();
#pragma unroll
    for (int ks = 0; ks < 2; ks++) {
      bf16x8 av[4], bv[4];
#pragma unroll
      for (int m = 0; m < 4; m++) {
        const int row = wr * 64 + m * 16 + l16;
        const int ch = (ks * 4 + lhi) ^ (row & 7);
        av[m] = *(const bf16x8*)((const char*)As + row * 128 + ch * 16);
      }
#pragma unroll
      for (int n = 0; n < 4; n++) {
        const int row = wc * 64 + n * 16 + l16;
        const int ch = (ks * 4 + lhi) ^ (row & 7);
        bv[n] = *(const bf16x8*)((const char*)Bs + row * 128 + ch * 16);
      }
#pragma unroll
      for (int m = 0; m < 4; m++)
#pragma unroll
        for (int n = 0; n < 4; n++)
          acc[m][n] = __builtin_amdgcn_mfma_f32_16x16x32_bf16(av[m], bv[n],
                                                              acc[m][n], 0, 0, 0);
    }
    __syncthreads();
  }

#pragma unroll
  for (int m = 0; m < 4; m++) {
#pragma unroll
    for (int n = 0; n < 4; n++) {
      const long col = rB0 + wc * 64 + n * 16 + l16;
      const float bsv = bias[col];
#pragma unroll
      for (int r = 0; r < 4; r++) {
        const long row = rA0 + wr * 64 + m * 16 + lhi * 4 + r;
        float v = acc[m][n][r] + bsv;
        if (MODE == 1) v = 0.5f * v * (1.f + erff(v * 0.7071067811865475f));
        if (MODE == 2) {
          v += residF[row * N + col] + bf2f(residB[row * N + col]);
          ((float*)Cout)[row * N + col] = v;
        } else {
          ((unsigned short*)Cout)[row * N + col] = f2bf(v);
        }
      }
    }
  }
}

// -- flash v5: 8 waves, KVBLK=64, dynamic big-first, dbuf + counted vmcnt ---
// QF/KF: [bh][s][128] f16; VT: [bh][128][s] bf16; AO: [b][s][h*128+d] bf16
__global__ __launch_bounds__(512, 2) void flash(
    const unsigned short* __restrict__ QF, const unsigned short* __restrict__ KF,
    const unsigned short* __restrict__ VT, const float* __restrict__ amask,
    unsigned short* __restrict__ AO) {
  __shared__ unsigned short Kt[2][64 * 128];  // 32KB [key][d] f16, dbuf
  __shared__ unsigned short Vt[2][128 * 64];  // 32KB [d][key] bf16, dbuf
  __shared__ unsigned short Pl[8 * 1024];     // 16KB per-wave 16x64 P bf16
  __shared__ float maskL[SS];                 //  8KB amask*log2e => 88KB total
  // big-first (LPT) dispatch: all qt=15 blocks first, then 14, ...
  const int z = blockIdx.x;
  const int qt = 15 - (z >> 5);
  const int bh = z & 31;
  const int b = bh >> 4, h = bh & 15;
  const int tid = threadIdx.x, wid = tid >> 6, lane = tid & 63;
  const int l16 = lane & 15, lhi = lane >> 4;
  const unsigned short* Qfb = QF + (long)bh * SS * HD;
  const unsigned short* Kfb = KF + (long)bh * SS * HD;
  const unsigned short* Vb = VT + (long)bh * HD * SS;
  const int q0 = qt * 128 + wid * 16;  // 16 q-rows per wave
  const float LOG2E = 1.4426950408889634f;
  const float SCL2 = 16.322232154552f;  // sqrt(128)*log2e

  {  // amask row -> LDS (prescaled); K-loop stays free of global loads
    float4 m0 = ((const float4*)(amask + (long)b * SS))[tid];
    m0.x *= LOG2E; m0.y *= LOG2E; m0.z *= LOG2E; m0.w *= LOG2E;
    ((float4*)maskL)[tid] = m0;
  }

  f16x8 qf[4];
#pragma unroll
  for (int ks = 0; ks < 4; ks++)
    qf[ks] = *(const f16x8*)(Qfb + (long)(q0 + l16) * HD + ks * 32 + lhi * 8);

  // stage tile kt2 (64 keys): 4 loads/thread x 512 thr = 32KB
  auto stage = [&](int kt2, int bu) {
#pragma unroll
    for (int i = 0; i < 2; i++) {
      const int lin = i * 8192 + wid * 1024 + (lane << 4);
      const int dst = i * 8192 + wid * 1024;
      {
        const int row = lin >> 8;  // K rows are 256B (128 f16)
        const int cs = ((lin >> 4) & 15) ^ (row & 7);
        gll16(Kfb + (long)(kt2 * 64 + row) * HD + cs * 8,
              (const char*)Kt[bu] + dst);
      }
      {
        const int row = lin >> 7;  // V rows are 128B (64 bf16 keys)
        const int cs = ((lin >> 4) & 7) ^ (row & 7);
        gll16(Vb + (long)row * SS + kt2 * 64 + cs * 8, (const char*)Vt[bu] + dst);
      }
    }
  };

  f32x4 accO[8] = {};
  float mrow[4], lrow[4];
#pragma unroll
  for (int r = 0; r < 4; r++) { mrow[r] = -3e38f; lrow[r] = 0.f; }

  const int nkt = 2 * qt + 2;
  stage(0, 0);
  asm volatile("s_waitcnt lgkmcnt(0)" ::: "memory");  // maskL writes done
  int buf = 0;
  for (int kt = 0; kt < nkt; kt++) {
    if (kt + 1 < nkt) {
      stage(kt + 1, buf ^ 1);  // 4 loads stay in flight across the barrier
      asm volatile("s_waitcnt vmcnt(4)" ::: "memory");  // tile kt landed
    } else {
      asm volatile("s_waitcnt vmcnt(0)" ::: "memory");
    }
    __builtin_amdgcn_s_barrier();  // raw barrier: no vmcnt(0) drain

    // wave-uniform causal skip (all this wave's rows above the key range)
    const bool active = (kt * 64 <= q0 + 15);
    if (active) {
      // S = Q K^T (f16, 16 MFMAs)
      f32x4 accS[4] = {};
      __builtin_amdgcn_s_setprio(1);
#pragma unroll
      for (int ks = 0; ks < 4; ks++) {
        f16x8 bk[4];
#pragma unroll
        for (int nf = 0; nf < 4; nf++) {
          const int row = nf * 16 + l16;
          const int ch = (ks * 4 + lhi) ^ (row & 7);
          bk[nf] = *(const f16x8*)((const char*)Kt[buf] + row * 256 + ch * 16);
        }
#pragma unroll
        for (int nf = 0; nf < 4; nf++)
          accS[nf] = __builtin_amdgcn_mfma_f32_16x16x32_f16(qf[ks], bk[nf],
                                                            accS[nf], 0, 0, 0);
      }
      __builtin_amdgcn_s_setprio(0);

      // scale to log2 domain + mask + causal
      float mk[4];
#pragma unroll
      for (int nf = 0; nf < 4; nf++) mk[nf] = maskL[kt * 64 + nf * 16 + l16];
#pragma unroll
      for (int nf = 0; nf < 4; nf++)
#pragma unroll
        for (int r = 0; r < 4; r++) {
          const int key = kt * 64 + nf * 16 + l16;
          const int qg = q0 + lhi * 4 + r;
          const float sv = accS[nf][r] * SCL2 + mk[nf];
          accS[nf][r] = (key > qg) ? -1e30f : sv;
        }

      // row maxes over the 16-lane group
      float mx[4];
#pragma unroll
      for (int r = 0; r < 4; r++) {
        float m0 = fmaxf(fmaxf(accS[0][r], accS[1][r]),
                         fmaxf(accS[2][r], accS[3][r]));
        m0 = fmaxf(m0, __shfl_xor(m0, 1));
        m0 = fmaxf(m0, __shfl_xor(m0, 2));
        m0 = fmaxf(m0, __shfl_xor(m0, 4));
        m0 = fmaxf(m0, __shfl_xor(m0, 8));
        mx[r] = m0;
      }
      // defer-rescale (THR=8 in log2 domain)
      bool defer = true;
#pragma unroll
      for (int r = 0; r < 4; r++) defer = defer && (mx[r] <= mrow[r] + 8.f);
      if (!__all(defer)) {
#pragma unroll
        for (int r = 0; r < 4; r++) {
          const float mnew = fmaxf(mrow[r], mx[r]);
          const float alpha = exp2f(mrow[r] - mnew);
          mrow[r] = mnew;
          lrow[r] *= alpha;
#pragma unroll
          for (int nf2 = 0; nf2 < 8; nf2++) accO[nf2][r] *= alpha;
        }
      }
      // P = exp2(S - m) -> per-wave LDS (16x64 bf16, 128B rows, swizzled)
#pragma unroll
      for (int r = 0; r < 4; r++) {
        const int rowl = lhi * 4 + r;
        const int qg = q0 + rowl;
        float rsum = 0.f;
#pragma unroll
        for (int nf = 0; nf < 4; nf++) {
          const int key = kt * 64 + nf * 16 + l16;
          const float p = (key > qg) ? 0.f : exp2f(accS[nf][r] - mrow[r]);
          rsum += p;
          const int colv = nf * 16 + l16;
          const int slot = (colv >> 3) ^ (rowl & 7);
          *(unsigned short*)((char*)Pl + wid * 2048 + rowl * 128 + slot * 16 +
                             (colv & 7) * 2) = f2bf(p);
        }
        rsum += __shfl_xor(rsum, 1);
        rsum += __shfl_xor(rsum, 2);
        rsum += __shfl_xor(rsum, 4);
        rsum += __shfl_xor(rsum, 8);
        lrow[r] += rsum;
      }

      // O += P V  (16 MFMAs, bf16)
      __builtin_amdgcn_s_setprio(1);
#pragma unroll
      for (int ks2 = 0; ks2 < 2; ks2++) {
        const int chp = (ks2 * 4 + lhi) ^ (l16 & 7);
        bf16x8 pa =
            *(const bf16x8*)((const char*)Pl + wid * 2048 + l16 * 128 + chp * 16);
#pragma unroll
        for (int nf2 = 0; nf2 < 8; nf2++) {
          const int rowv = nf2 * 16 + l16;
          const int ch = (ks2 * 4 + lhi) ^ (rowv & 7);
          bf16x8 vv =
              *(const bf16x8*)((const char*)Vt[buf] + rowv * 128 + ch * 16);
          accO[nf2] = __builtin_amdgcn_mfma_f32_16x16x32_bf16(pa, vv,
                                                              accO[nf2], 0, 0, 0);
        }
      }
      __builtin_amdgcn_s_setprio(0);
    }  // active
    __builtin_amdgcn_s_barrier();  // all waves done with buf before restage
    buf ^= 1;
  }

#pragma unroll
  for (int nf2 = 0; nf2 < 8; nf2++)
#pragma unroll
    for (int r = 0; r < 4; r++) {
      const int qg = q0 + lhi * 4 + r;
      const int d = nf2 * 16 + l16;
      const float v = accO[nf2][r] / lrow[r];
      AO[((long)(b * SS + qg)) * HID + h * HD + d] = f2bf(v);
    }
}

extern "C" void kernel_launch(void* const* d_in, const int* in_sizes, int n_in,
                              void* d_out, int out_size, void* d_ws,
                              size_t ws_size, hipStream_t stream) {
  (void)in_sizes; (void)n_in; (void)out_size;
  const float* hidden = (const float*)d_in[0];
  const float* amask = (const float*)d_in[1];
  const float* w_qkv = (const float*)d_in[2];
  const float* b_qkv = (const float*)d_in[3];
  const float* w_o = (const float*)d_in[4];
  const float* b_o = (const float*)d_in[5];
  const float* ln1s = (const float*)d_in[6];
  const float* ln1b = (const float*)d_in[7];
  const float* ln2s = (const float*)d_in[8];
  const float* ln2b = (const float*)d_in[9];
  const float* w_in = (const float*)d_in[10];
  const float* b_in = (const float*)d_in[11];
  const float* w_out = (const float*)d_in[12];
  const float* b_out = (const float*)d_in[13];

  char* ws = (char*)d_ws;
  // liveness-aliased workspace (<=170MB; >=209MB verified available)
  unsigned short* X1f = (unsigned short*)(ws + 0);           // 16MB f16, later AO
  unsigned short* X2  = (unsigned short*)(ws + 16777216);    // 16MB bf16
  unsigned short* Vbf = (unsigned short*)(ws + 33554432);    // 16MB bf16
  unsigned short* WQ  = (unsigned short*)(ws + 50331648);    // 24MB f16 [6144][2048]
  unsigned short* QFb = (unsigned short*)(ws + 75497472);    // 16MB f16
  unsigned short* KFb = (unsigned short*)(ws + 92274688);    // 16MB f16
  unsigned short* VTb = (unsigned short*)(ws + 109051904);   // 16MB bf16
  unsigned short* ATT = (unsigned short*)(ws + 125829120);   // 16MB bf16
  unsigned short* WD  = (unsigned short*)(ws + 142606336);   // 32MB bf16 (Wo/Win/Wout)
  float2* ROPE = (float2*)(ws + 176160768);                  // 1MB
  if (ws_size < 177209344) return;

  unsigned short* AO = X1f;  // x1 dead after gemmqkv
  unsigned short* H1 = WQ;   // WQ+QF+KF dead after flash: 64MB region

  ln2k<<<MT, 256, 0, stream>>>(hidden, ln1s, ln1b, ln2s, ln2b, X1f, X2);
  rope_tab<<<SS, 64, 0, stream>>>(ROPE);
  // qkv: one f16 GEMM, rope fused for q,k
  wtrans<true><<<dim3(192, 64), dim3(32, 8), 0, stream>>>(w_qkv, WQ, HID,
                                                          3 * HID, 3 * HID, 0);
  gemmqkv<<<dim3(48, 32), 256, 0, stream>>>(X1f, WQ, b_qkv, ROPE, QFb, KFb,
                                            Vbf);
  vtrans<<<dim3(4, 64, 32), dim3(32, 8), 0, stream>>>(Vbf, VTb);
  flash<<<512, 512, 0, stream>>>(QFb, KFb, VTb, amask, AO);
  // attention projection
  wtrans<false><<<dim3(64, 64), dim3(32, 8), 0, stream>>>(w_o, WD, HID, HID,
                                                          HID, 0);
  gemm128<0><<<dim3(16, 32), 256, 0, stream>>>(AO, WD, b_o, ATT, MT, HID, HID,
                                               nullptr, nullptr);
  // mlp
  wtrans<false><<<dim3(256, 64), dim3(32, 8), 0, stream>>>(w_in, WD, HID,
                                                           INTER, INTER, 0);
  gemm128<1><<<dim3(64, 32), 256, 0, stream>>>(X2, WD, b_in, H1, MT, INTER,
                                               HID, nullptr, nullptr);
  wtrans<false><<<dim3(64, 256), dim3(32, 8), 0, stream>>>(w_out, WD, INTER,
                                                           HID, HID, 0);
  gemm128<2><<<dim3(16, 32), 256, 0, stream>>>(H1, WD, b_out, d_out, MT, HID,
                                               INTER, hidden, ATT);
}